// Round 2
// baseline (609.255 us; speedup 1.0000x reference)
//
#include <hip/hip_runtime.h>

// LiquidLoRA (fp32 I/O): out[s,o] = 2 * sum_r (sum_i x[s,i]*A[r,i]) * Beff[o,r]
// Kernel A: liquid dynamics in fp32 VALU -> Beff bf16 in d_ws (512 KB).
// Kernel B: fused skinny GEMM chain, bf16 MFMA, fp32 loads/stores.
// Roofline: 536 MB HBM (x + out) -> ~85 us floor at 6.3 TB/s.

typedef __attribute__((ext_vector_type(8))) short short8;
typedef __attribute__((ext_vector_type(4))) short short4_t;
typedef __attribute__((ext_vector_type(4))) float f32x4;

static __device__ __forceinline__ unsigned short f2bf(float f) {
    unsigned int x;
    __builtin_memcpy(&x, &f, 4);
    x += 0x7fffu + ((x >> 16) & 1);   // round-to-nearest-even
    return (unsigned short)(x >> 16);
}
static __device__ __forceinline__ float bf2f(unsigned short u) {
    unsigned int x = ((unsigned int)u) << 16;
    float f;
    __builtin_memcpy(&f, &x, 4);
    return f;
}

// ---------------- Kernel A: liquid dynamics (fp32) -> Beff [4096][64] bf16 ----
// grid 256 x block 256. Block = 16 O-rows; thread (row, cg) owns 4 cols.
__global__ __launch_bounds__(256) void liquid_kernel(
    const float* __restrict__ loraB,    // [4096][64]
    const float* __restrict__ hiddenB,  // [4096][64]
    const float* __restrict__ Wg,       // [64][128]
    const float* __restrict__ bg,       // [64]
    const float* __restrict__ Wt,       // [64][128]
    const float* __restrict__ bt,       // [64]
    unsigned short* __restrict__ beff)  // [4096][64] bf16
{
    __shared__ __align__(16) float inp[16][132];   // [target(64) | h(64)], pad
    const int tid = threadIdx.x;
    const int row = tid >> 4;       // 0..15
    const int cg  = tid & 15;       // 0..15
    const int orow = blockIdx.x * 16 + row;
    const int c0 = cg * 4;

    float tgt[4], h[4], bgv[4], btv[4];
#pragma unroll
    for (int i = 0; i < 4; ++i) {
        tgt[i] = loraB[orow * 64 + c0 + i];
        h[i]   = hiddenB[orow * 64 + c0 + i];
        bgv[i] = bg[c0 + i];
        btv[i] = bt[c0 + i];
        inp[row][c0 + i] = tgt[i];     // target half, written once
    }
    for (int step = 0; step < 3; ++step) {
#pragma unroll
        for (int i = 0; i < 4; ++i) inp[row][64 + c0 + i] = h[i];
        __syncthreads();
        float dg[4], dt_[4];
#pragma unroll
        for (int c = 0; c < 4; ++c) { dg[c] = bgv[c]; dt_[c] = btv[c]; }
        for (int k = 0; k < 128; k += 4) {
            f32x4 iv = *(f32x4*)&inp[row][k];
#pragma unroll
            for (int c = 0; c < 4; ++c) {
                f32x4 wgv = *(const f32x4*)&Wg[(c0 + c) * 128 + k];
                f32x4 wtv = *(const f32x4*)&Wt[(c0 + c) * 128 + k];
                dg[c]  += iv[0]*wgv[0] + iv[1]*wgv[1] + iv[2]*wgv[2] + iv[3]*wgv[3];
                dt_[c] += iv[0]*wtv[0] + iv[1]*wtv[1] + iv[2]*wtv[2] + iv[3]*wtv[3];
            }
        }
#pragma unroll
        for (int c = 0; c < 4; ++c) {
            float f   = 1.f / (1.f + __expf(-dg[c]));
            float tau = 0.1f + 9.9f / (1.f + __expf(-dt_[c]));
            float a   = 1.f / tau + f;
            float dec = __expf(-a * 0.1f);
            h[c] = h[c] * dec + (f / a) * tgt[c] * (1.f - dec);
        }
        __syncthreads();   // h-half writes of next step wait for all dot reads
    }
#pragma unroll
    for (int i = 0; i < 4; ++i)
        beff[orow * 64 + c0 + i] = f2bf(h[i]);
}

// ---------------- Kernel B: out = 2 * (x @ A^T) @ Beff^T ----------------
// grid 256 x block 512 (8 waves), M_blk=64.
// Phase 1: t[64x64] = x_blk @ A^T (BK=128, fp32->bf16 staging), t kept hi+lo bf16.
// Phase 2: O in 128-col chunks; 2x MFMA (hi,lo); fp32 bounce; float4 stores.
__global__ __launch_bounds__(512) void lora_gemm_kernel(
    const float* __restrict__ x,             // [16384][4096]
    const float* __restrict__ loraA,         // [64][4096]
    const unsigned short* __restrict__ beff, // [4096][64] bf16
    float* __restrict__ out)                 // [16384][4096]
{
    __shared__ __align__(16) union {
        struct { unsigned short xs[64 * 136]; unsigned short as[64 * 136]; } p1;
        struct { unsigned short bs[128 * 72]; float bounce[64 * 132]; } p2;
    } sm;
    __shared__ __align__(16) unsigned short tsh[64 * 72];
    __shared__ __align__(16) unsigned short tsl[64 * 72];

    const int tid  = threadIdx.x;
    const int lane = tid & 63;
    const int w    = tid >> 6;
    const int q    = lane >> 4;
    const int ln   = lane & 15;
    const int m0   = blockIdx.x * 64;
    const int ms   = (w >> 1) * 16;   // m-strip (block-local)
    const int nb   = (w & 1) * 32;    // phase-1 n-half

    f32x4 acc0 = (f32x4){0.f, 0.f, 0.f, 0.f};
    f32x4 acc1 = (f32x4){0.f, 0.f, 0.f, 0.f};

    // ---- phase 1: t = x_blk @ A^T ----
    for (int k0 = 0; k0 < 4096; k0 += 128) {
        f32x4 xv[4], av[4];
#pragma unroll
        for (int i = 0; i < 4; ++i) {
            int c = tid + i * 512;            // 2048 float4 chunks
            int r = c >> 5, c4 = (c & 31) * 4;
            xv[i] = *(const f32x4*)&x[(size_t)(m0 + r) * 4096 + k0 + c4];
            av[i] = *(const f32x4*)&loraA[(size_t)r * 4096 + k0 + c4];
        }
        __syncthreads();                      // prev iter's LDS reads done
#pragma unroll
        for (int i = 0; i < 4; ++i) {
            int c = tid + i * 512;
            int r = c >> 5, c4 = (c & 31) * 4;
            short4_t xb, ab;
#pragma unroll
            for (int j = 0; j < 4; ++j) {
                xb[j] = (short)f2bf(xv[i][j]);
                ab[j] = (short)f2bf(av[i][j]);
            }
            *(short4_t*)&sm.p1.xs[r * 136 + c4] = xb;
            *(short4_t*)&sm.p1.as[r * 136 + c4] = ab;
        }
        __syncthreads();
#pragma unroll
        for (int kk = 0; kk < 128; kk += 32) {
            short8 af = *(short8*)&sm.p1.xs[(ms + ln) * 136 + kk + q * 8];
            short8 b0 = *(short8*)&sm.p1.as[(nb + ln) * 136 + kk + q * 8];
            short8 b1 = *(short8*)&sm.p1.as[(nb + 16 + ln) * 136 + kk + q * 8];
            acc0 = __builtin_amdgcn_mfma_f32_16x16x32_bf16(af, b0, acc0, 0, 0, 0);
            acc1 = __builtin_amdgcn_mfma_f32_16x16x32_bf16(af, b1, acc1, 0, 0, 0);
        }
    }
    // park t as hi+lo bf16 (error ~2^-16); wave-private writes, synced below
#pragma unroll
    for (int r = 0; r < 4; ++r) {
        float v0 = acc0[r], v1 = acc1[r];
        unsigned short h0 = f2bf(v0), h1 = f2bf(v1);
        tsh[(ms + q * 4 + r) * 72 + nb + ln]      = h0;
        tsl[(ms + q * 4 + r) * 72 + nb + ln]      = f2bf(v0 - bf2f(h0));
        tsh[(ms + q * 4 + r) * 72 + nb + 16 + ln] = h1;
        tsl[(ms + q * 4 + r) * 72 + nb + 16 + ln] = f2bf(v1 - bf2f(h1));
    }

    // ---- phase 2: out_blk = 2 * t @ Beff^T ----
    const int nb2 = (w & 1) * 64;
    for (int o0 = 0; o0 < 4096; o0 += 128) {
        short8 bv[2];
#pragma unroll
        for (int i = 0; i < 2; ++i) {
            int c = tid + i * 512;            // 1024 bf16x8 chunks
            int r = c >> 3, c8 = (c & 7) * 8;
            bv[i] = *(const short8*)&beff[(size_t)(o0 + r) * 64 + c8];
        }
        __syncthreads();   // iter0: ts writes + phase-1 LDS reads done; else: bounce reads done
#pragma unroll
        for (int i = 0; i < 2; ++i) {
            int c = tid + i * 512;
            int r = c >> 3, c8 = (c & 7) * 8;
            *(short8*)&sm.p2.bs[r * 72 + c8] = bv[i];
        }
        __syncthreads();
        f32x4 a2[4];
#pragma unroll
        for (int t = 0; t < 4; ++t) a2[t] = (f32x4){0.f, 0.f, 0.f, 0.f};
#pragma unroll
        for (int kk = 0; kk < 64; kk += 32) {
            short8 ah = *(short8*)&tsh[(ms + ln) * 72 + kk + q * 8];
            short8 al = *(short8*)&tsl[(ms + ln) * 72 + kk + q * 8];
#pragma unroll
            for (int t = 0; t < 4; ++t) {
                short8 bf = *(short8*)&sm.p2.bs[(nb2 + t * 16 + ln) * 72 + kk + q * 8];
                a2[t] = __builtin_amdgcn_mfma_f32_16x16x32_bf16(ah, bf, a2[t], 0, 0, 0);
                a2[t] = __builtin_amdgcn_mfma_f32_16x16x32_bf16(al, bf, a2[t], 0, 0, 0);
            }
        }
#pragma unroll
        for (int t = 0; t < 4; ++t)
#pragma unroll
            for (int r = 0; r < 4; ++r)
                sm.p2.bounce[(ms + q * 4 + r) * 132 + nb2 + t * 16 + ln] =
                    a2[t][r] * 2.0f;
        __syncthreads();
#pragma unroll
        for (int i = 0; i < 4; ++i) {
            int c = tid + i * 512;            // 2048 float4 chunks
            int r = c >> 5, c4 = (c & 31) * 4;
            *(f32x4*)&out[(size_t)(m0 + r) * 4096 + o0 + c4] =
                *(f32x4*)&sm.p2.bounce[r * 132 + c4];
        }
    }
}

extern "C" void kernel_launch(void* const* d_in, const int* in_sizes, int n_in,
                              void* d_out, int out_size, void* d_ws, size_t ws_size,
                              hipStream_t stream) {
    const float* x       = (const float*)d_in[0];
    const float* loraA   = (const float*)d_in[1];
    const float* loraB   = (const float*)d_in[2];
    const float* hiddenB = (const float*)d_in[3];
    const float* Wg      = (const float*)d_in[4];
    const float* bg      = (const float*)d_in[5];
    const float* Wt      = (const float*)d_in[6];
    const float* bt      = (const float*)d_in[7];
    float* out = (float*)d_out;
    unsigned short* beff = (unsigned short*)d_ws;   // 4096*64 bf16 = 512 KB

    hipLaunchKernelGGL(liquid_kernel, dim3(256), dim3(256), 0, stream,
                       loraB, hiddenB, Wg, bg, Wt, bt, beff);
    hipLaunchKernelGGL(lora_gemm_kernel, dim3(256), dim3(512), 0, stream,
                       x, loraA, beff, out);
}